// Round 13
// baseline (216.188 us; speedup 1.0000x reference)
//
#include <hip/hip_runtime.h>
#include <cfloat>

#define KC    32768
#define NPTS  8192
#define TPB   256
#define PPT   8
#define PTS_PER_BLK (TPB * PPT)        // 2048
#define NPB   (NPTS / PTS_PER_BLK)     // 4

typedef float v2f __attribute__((ext_vector_type(2)));

// Packed fp32 (IEEE per 32-bit half) — bit-identical to scalar chain (verified R1-R12)
__device__ __forceinline__ v2f pk_fma(v2f a, v2f b, v2f c) {
    v2f d; asm("v_pk_fma_f32 %0, %1, %2, %3" : "=v"(d) : "v"(a), "v"(b), "v"(c)); return d;
}
__device__ __forceinline__ v2f pk_add(v2f a, v2f b) {
    v2f d; asm("v_pk_add_f32 %0, %1, %2" : "=v"(d) : "v"(a), "v"(b)); return d;
}
// Broadcast half H of PAIR src0 to both result halves (VOP3P op_sel; verified R12)
template<int H>
__device__ __forceinline__ v2f pk_mul_s(v2f a, v2f b) {
    v2f d;
    if constexpr (H == 0)
        asm("v_pk_mul_f32 %0, %1, %2 op_sel:[0,0] op_sel_hi:[0,1]" : "=v"(d) : "v"(a), "v"(b));
    else
        asm("v_pk_mul_f32 %0, %1, %2 op_sel:[1,0] op_sel_hi:[1,1]" : "=v"(d) : "v"(a), "v"(b));
    return d;
}
template<int H>
__device__ __forceinline__ v2f pk_fma_s(v2f a, v2f b, v2f c) {
    v2f d;
    if constexpr (H == 0)
        asm("v_pk_fma_f32 %0, %1, %2, %3 op_sel:[0,0,0] op_sel_hi:[0,1,1]" : "=v"(d) : "v"(a), "v"(b), "v"(c));
    else
        asm("v_pk_fma_f32 %0, %1, %2, %3 op_sel:[1,0,0] op_sel_hi:[1,1,1]" : "=v"(d) : "v"(a), "v"(b), "v"(c));
    return d;
}
__device__ __forceinline__ float min3f(float a, float b, float c) {
    float d; asm("v_min3_f32 %0, %1, %2, %3" : "=v"(d) : "v"(a), "v"(b), "v"(c)); return d;
}

// ---------------- K1: per-chunk MIN-DISTANCE ONLY (no index), 8 points/thread
template<int NC>
__global__ __launch_bounds__(TPB, 8) void k_dist(const float* __restrict__ x,
                                                 const float* __restrict__ E,
                                                 float* __restrict__ dmn) {
#pragma clang fp contract(off)
    constexpr int CHUNK = KC / NC;
    __shared__ __align__(16) float lds[5 * CHUNK];
    float* exL = lds;
    float* eyL = lds + CHUNK;
    float* ezL = lds + 2 * CHUNK;
    float* ewL = lds + 3 * CHUNK;
    float* bL  = lds + 4 * CHUNK;

    const int chunk = blockIdx.x;
    const int pblk  = blockIdx.y;
    const int tid   = threadIdx.x;
    const int kbase = chunk * CHUNK;

    // Issue x loads FIRST (HBM/L2 latency hides under LDS staging + barrier)
    float xr[PPT][4];
#pragma unroll
    for (int i = 0; i < PPT; ++i) {
        const int p  = pblk * PTS_PER_BLK + i * TPB + tid;
        const int t  = p >> 12, s = p & 4095;
        const int xb = t * 16384 + s;
        xr[i][0] = x[xb];
        xr[i][1] = x[xb + 4096];
        xr[i][2] = x[xb + 8192];
        xr[i][3] = x[xb + 12288];
    }

    // Stage SoA + fused bnorm (squares individually rounded, sequential adds)
    for (int i = tid; i < CHUNK; i += TPB) {
        float4 e = ((const float4*)E)[kbase + i];
        exL[i] = e.x; eyL[i] = e.y; ezL[i] = e.z; ewL[i] = e.w;
        bL[i]  = ((e.x * e.x + e.y * e.y) + e.z * e.z) + e.w * e.w;
    }
    __syncthreads();

    // packed pairs X01={x0,x1}, X23={x2,x3}, Av={a,a}
    v2f X01[PPT], X23[PPT], Av[PPT];
#pragma unroll
    for (int i = 0; i < PPT; ++i) {
        const float x0 = xr[i][0], x1 = xr[i][1], x2 = xr[i][2], x3 = xr[i][3];
        X01[i] = v2f{x0, x1};
        X23[i] = v2f{x2, x3};
        const float a = ((x0 * x0 + x1 * x1) + x2 * x2) + x3 * x3;
        Av[i] = v2f{a, a};
    }
    const v2f M2 = {-2.0f, -2.0f};

    float bd[PPT];
#pragma unroll
    for (int i = 0; i < PPT; ++i) bd[i] = FLT_MAX;

#pragma unroll 4
    for (int q = 0; q < CHUNK / 4; ++q) {      // 4 codes x 8 points per iter
        float4 vx = *(const float4*)(exL + 4 * q);
        float4 vy = *(const float4*)(eyL + 4 * q);
        float4 vz = *(const float4*)(ezL + 4 * q);
        float4 vw = *(const float4*)(ewL + 4 * q);
        float4 vb = *(const float4*)(bL  + 4 * q);

        const v2f ex0 = {vx.x, vx.y}, ex1 = {vx.z, vx.w};
        const v2f ey0 = {vy.x, vy.y}, ey1 = {vy.z, vy.w};
        const v2f ez0 = {vz.x, vz.y}, ez1 = {vz.z, vz.w};
        const v2f ew0 = {vw.x, vw.y}, ew1 = {vw.z, vw.w};
        const v2f b0  = {vb.x, vb.y}, b1  = {vb.z, vb.w};

#pragma unroll
        for (int i = 0; i < PPT; ++i) {
            // m = fma(x3,ew, fma(x2,ez, fma(x1,ey, x0*ex)))  (BLAS chain, R1-verified)
            v2f m0 = pk_fma_s<1>(X23[i], ew0, pk_fma_s<0>(X23[i], ez0,
                      pk_fma_s<1>(X01[i], ey0, pk_mul_s<0>(X01[i], ex0))));
            v2f m1 = pk_fma_s<1>(X23[i], ew1, pk_fma_s<0>(X23[i], ez1,
                      pk_fma_s<1>(X01[i], ey1, pk_mul_s<0>(X01[i], ex1))));
            // d = fma(-2,m,(a+b)) == (a+b) - fl(2m) bitwise
            v2f d0 = pk_fma(M2, m0, pk_add(Av[i], b0));
            v2f d1 = pk_fma(M2, m1, pk_add(Av[i], b1));
            bd[i] = min3f(min3f(bd[i], d0.x, d0.y), d1.x, d1.y);  // min only
        }
    }
#pragma unroll
    for (int i = 0; i < PPT; ++i) {
        const int p = pblk * PTS_PER_BLK + i * TPB + tid;
        dmn[chunk * NPTS + p] = bd[i];
    }
}

// ---------------- K2: merge chunk-mins, recover first-index k, gather, loss
// dmin = min over chunk-mins (exact). First chunk whose min == dmin holds the
// reference's first-index argmin; rescan it with the bitwise-identical scalar
// chain to find the first k. (Verified absmax 0.0 in R12.)
template<int NC>
__global__ __launch_bounds__(256) void k_merge(const float* __restrict__ x,
                                               const float* __restrict__ E,
                                               const float* __restrict__ dmn,
                                               float* __restrict__ out,
                                               double* __restrict__ partials) {
#pragma clang fp contract(off)
    constexpr int CHUNK = KC / NC;
    const int tid  = threadIdx.x;
    const int sub  = tid & 7;
    const int pidx = tid >> 3;                 // 0..31
    const int p    = blockIdx.x * 32 + pidx;   // 256 blocks x 32 points
    const int t    = p >> 12, s = p & 4095;
    const int xb   = t * 16384 + s;

    const float x0 = x[xb];
    const float x1 = x[xb + 4096];
    const float x2 = x[xb + 8192];
    const float x3 = x[xb + 12288];
    const float a  = ((x0 * x0 + x1 * x1) + x2 * x2) + x3 * x3;

    // min over chunks, tie -> smaller chunk id (lexicographic)
    float bd = FLT_MAX;
    int   bc = 0x7fffffff;
#pragma unroll 8
    for (int i = 0; i < NC / 8; ++i) {
        const int c = sub + 8 * i;             // ascending per sub
        float d = dmn[c * NPTS + p];
        if (d < bd) { bd = d; bc = c; }        // strict <: earliest c in sub set
    }
#pragma unroll
    for (int m = 1; m <= 4; m <<= 1) {
        float d2 = __shfl_xor(bd, m);
        int   c2 = __shfl_xor(bc, m);
        if (d2 < bd || (d2 == bd && c2 < bc)) { bd = d2; bc = c2; }
    }

    // rescan chunk bc: sub handles CHUNK/8 consecutive codes
    const int kb = bc * CHUNK;
    int jloc = 1 << 30;
    for (int jj = 0; jj < CHUNK / 8; ++jj) {
        const int j = sub * (CHUNK / 8) + jj;
        float4 e = ((const float4*)E)[kb + j];
        float bn = ((e.x * e.x + e.y * e.y) + e.z * e.z) + e.w * e.w;
        float m_ = __builtin_fmaf(x3, e.w, __builtin_fmaf(x2, e.z,
                    __builtin_fmaf(x1, e.y, x0 * e.x)));
        float t_ = a + bn;
        float d_ = __builtin_fmaf(-2.0f, m_, t_);
        if (d_ == bd) jloc = min(jloc, j);     // ascending j -> first match
    }
#pragma unroll
    for (int m = 1; m <= 4; m <<= 1) jloc = min(jloc, __shfl_xor(jloc, m));
    const int bk = kb + (jloc & (CHUNK - 1));  // clamp guards OOB if mismatch

    double ls = 0.0;
    if (sub < 4) {                             // one channel per sub-lane
        const int ch  = sub;
        const int idx = xb + ch * 4096;
        float xv   = x[idx];
        float ev   = E[bk * 4 + ch];
        float diff = ev - xv;                  // fl(z_q - x)
        float sq   = diff * diff;              // fl(diff^2)
        out[idx]   = xv + diff;                // z_q_st = fl(x + fl(z_q - x))
        ls = (double)sq;
        if (ch == 0) out[32769 + p] = (float)bk;  // codes as float
    }
#pragma unroll
    for (int m = 1; m < 64; m <<= 1) ls += __shfl_xor(ls, m);
    __shared__ double sred[4];
    if ((tid & 63) == 0) sred[tid >> 6] = ls;
    __syncthreads();
    if (tid == 0) partials[blockIdx.x] = sred[0] + sred[1] + sred[2] + sred[3];
}

// ---------------- K3: finalize qloss
__global__ void k_loss(const double* __restrict__ partials,
                       float* __restrict__ out) {
#pragma clang fp contract(off)
    if (threadIdx.x == 0 && blockIdx.x == 0) {
        double sum = 0.0;
        for (int i = 0; i < 256; ++i) sum += partials[i];
        float mu = (float)(sum * (1.0 / 32768.0));   // /32768 exact
        float q  = mu + 0.1f * mu;                   // mean1 + BETA*mean2
        out[32768] = q;
    }
}

extern "C" void kernel_launch(void* const* d_in, const int* in_sizes, int n_in,
                              void* d_out, int out_size, void* d_ws, size_t ws_size,
                              hipStream_t stream) {
    const float* x = (const float*)d_in[0];   // (1,2,4,64,64)
    const float* E = (const float*)d_in[1];   // (32768,4)
    float* out = (float*)d_out;               // 40961 floats

    char* ws = (char*)d_ws;
    double* partials = (double*)ws;                    // 2 KB
    float*  dmn      = (float*)(ws + 2048);

    // dmn bytes = NC*8192*4: NC=512 -> 16 MiB (same ws footprint proven R10)
    const size_t need512 = 2048 + (size_t)512 * NPTS * 4;
    if (ws_size >= need512) {
        dim3 g(512, NPB);
        k_dist<512><<<g, TPB, 0, stream>>>(x, E, dmn);
        k_merge<512><<<NPTS / 32, 256, 0, stream>>>(x, E, dmn, out, partials);
    } else {
        dim3 g(256, NPB);
        k_dist<256><<<g, TPB, 0, stream>>>(x, E, dmn);
        k_merge<256><<<NPTS / 32, 256, 0, stream>>>(x, E, dmn, out, partials);
    }
    k_loss<<<1, 64, 0, stream>>>(partials, out);
}

// Round 14
// 54.468 us; speedup vs baseline: 3.9691x; 3.9691x over previous
//
#include <hip/hip_runtime.h>
#include <cfloat>

#define KC    32768
#define NPTS  8192
#define TPB   256
#define PPT   8
#define PTS_PER_BLK (TPB * PPT)        // 2048
#define NPB   (NPTS / PTS_PER_BLK)     // 4

typedef float v2f __attribute__((ext_vector_type(2)));

// Packed fp32 (IEEE per 32-bit half) — bit-identical to scalar chain (verified R1-R12)
__device__ __forceinline__ v2f pk_fma(v2f a, v2f b, v2f c) {
    v2f d; asm("v_pk_fma_f32 %0, %1, %2, %3" : "=v"(d) : "v"(a), "v"(b), "v"(c)); return d;
}
__device__ __forceinline__ v2f pk_add(v2f a, v2f b) {
    v2f d; asm("v_pk_add_f32 %0, %1, %2" : "=v"(d) : "v"(a), "v"(b)); return d;
}
// Broadcast half H of PAIR src0 to both result halves (VOP3P op_sel; verified R12)
template<int H>
__device__ __forceinline__ v2f pk_mul_s(v2f a, v2f b) {
    v2f d;
    if constexpr (H == 0)
        asm("v_pk_mul_f32 %0, %1, %2 op_sel:[0,0] op_sel_hi:[0,1]" : "=v"(d) : "v"(a), "v"(b));
    else
        asm("v_pk_mul_f32 %0, %1, %2 op_sel:[1,0] op_sel_hi:[1,1]" : "=v"(d) : "v"(a), "v"(b));
    return d;
}
template<int H>
__device__ __forceinline__ v2f pk_fma_s(v2f a, v2f b, v2f c) {
    v2f d;
    if constexpr (H == 0)
        asm("v_pk_fma_f32 %0, %1, %2, %3 op_sel:[0,0,0] op_sel_hi:[0,1,1]" : "=v"(d) : "v"(a), "v"(b), "v"(c));
    else
        asm("v_pk_fma_f32 %0, %1, %2, %3 op_sel:[1,0,0] op_sel_hi:[1,1,1]" : "=v"(d) : "v"(a), "v"(b), "v"(c));
    return d;
}
__device__ __forceinline__ float min3f(float a, float b, float c) {
    float d; asm("v_min3_f32 %0, %1, %2, %3" : "=v"(d) : "v"(a), "v"(b), "v"(c)); return d;
}

// ---------------- K1: per-chunk MIN-DISTANCE ONLY, 8 points/thread.
// EXACT R12 body (48 VGPR, no spills); occupancy comes from grid size only —
// NO min-waves in launch_bounds (R13's forced cap caused scratch spills).
template<int NC>
__global__ __launch_bounds__(TPB) void k_dist(const float* __restrict__ x,
                                              const float* __restrict__ E,
                                              float* __restrict__ dmn) {
#pragma clang fp contract(off)
    constexpr int CHUNK = KC / NC;
    __shared__ __align__(16) float lds[5 * CHUNK];
    float* exL = lds;
    float* eyL = lds + CHUNK;
    float* ezL = lds + 2 * CHUNK;
    float* ewL = lds + 3 * CHUNK;
    float* bL  = lds + 4 * CHUNK;

    const int chunk = blockIdx.x;
    const int pblk  = blockIdx.y;
    const int tid   = threadIdx.x;
    const int kbase = chunk * CHUNK;

    // Stage SoA + fused bnorm (squares individually rounded, sequential adds)
    for (int i = tid; i < CHUNK; i += TPB) {
        float4 e = ((const float4*)E)[kbase + i];
        exL[i] = e.x; eyL[i] = e.y; ezL[i] = e.z; ewL[i] = e.w;
        bL[i]  = ((e.x * e.x + e.y * e.y) + e.z * e.z) + e.w * e.w;
    }
    __syncthreads();

    // 8 points/thread: packed pairs X01={x0,x1}, X23={x2,x3}, Av={a,a}
    v2f X01[PPT], X23[PPT], Av[PPT];
#pragma unroll
    for (int i = 0; i < PPT; ++i) {
        const int p  = pblk * PTS_PER_BLK + i * TPB + tid;
        const int t  = p >> 12, s = p & 4095;
        const int xb = t * 16384 + s;
        const float x0 = x[xb];
        const float x1 = x[xb + 4096];
        const float x2 = x[xb + 8192];
        const float x3 = x[xb + 12288];
        X01[i] = v2f{x0, x1};
        X23[i] = v2f{x2, x3};
        const float a = ((x0 * x0 + x1 * x1) + x2 * x2) + x3 * x3;
        Av[i] = v2f{a, a};
    }
    const v2f M2 = {-2.0f, -2.0f};

    float bd[PPT];
#pragma unroll
    for (int i = 0; i < PPT; ++i) bd[i] = FLT_MAX;

#pragma unroll 2
    for (int q = 0; q < CHUNK / 4; ++q) {      // 4 codes x 8 points per iter
        float4 vx = *(const float4*)(exL + 4 * q);
        float4 vy = *(const float4*)(eyL + 4 * q);
        float4 vz = *(const float4*)(ezL + 4 * q);
        float4 vw = *(const float4*)(ewL + 4 * q);
        float4 vb = *(const float4*)(bL  + 4 * q);

        const v2f ex0 = {vx.x, vx.y}, ex1 = {vx.z, vx.w};
        const v2f ey0 = {vy.x, vy.y}, ey1 = {vy.z, vy.w};
        const v2f ez0 = {vz.x, vz.y}, ez1 = {vz.z, vz.w};
        const v2f ew0 = {vw.x, vw.y}, ew1 = {vw.z, vw.w};
        const v2f b0  = {vb.x, vb.y}, b1  = {vb.z, vb.w};

#pragma unroll
        for (int i = 0; i < PPT; ++i) {
            // m = fma(x3,ew, fma(x2,ez, fma(x1,ey, x0*ex)))  (BLAS chain, R1-verified)
            v2f m0 = pk_fma_s<1>(X23[i], ew0, pk_fma_s<0>(X23[i], ez0,
                      pk_fma_s<1>(X01[i], ey0, pk_mul_s<0>(X01[i], ex0))));
            v2f m1 = pk_fma_s<1>(X23[i], ew1, pk_fma_s<0>(X23[i], ez1,
                      pk_fma_s<1>(X01[i], ey1, pk_mul_s<0>(X01[i], ex1))));
            // d = fma(-2,m,(a+b)) == (a+b) - fl(2m) bitwise
            v2f d0 = pk_fma(M2, m0, pk_add(Av[i], b0));
            v2f d1 = pk_fma(M2, m1, pk_add(Av[i], b1));
            bd[i] = min3f(min3f(bd[i], d0.x, d0.y), d1.x, d1.y);  // min only
        }
    }
#pragma unroll
    for (int i = 0; i < PPT; ++i) {
        const int p = pblk * PTS_PER_BLK + i * TPB + tid;
        dmn[chunk * NPTS + p] = bd[i];
    }
}

// ---------------- K2: merge chunk-mins, recover first-index k, gather, loss
// (verified absmax 0.0 in R12 at NC=256; logic NC-independent)
template<int NC>
__global__ __launch_bounds__(256) void k_merge(const float* __restrict__ x,
                                               const float* __restrict__ E,
                                               const float* __restrict__ dmn,
                                               float* __restrict__ out,
                                               double* __restrict__ partials) {
#pragma clang fp contract(off)
    constexpr int CHUNK = KC / NC;
    const int tid  = threadIdx.x;
    const int sub  = tid & 7;
    const int pidx = tid >> 3;                 // 0..31
    const int p    = blockIdx.x * 32 + pidx;   // 256 blocks x 32 points
    const int t    = p >> 12, s = p & 4095;
    const int xb   = t * 16384 + s;

    const float x0 = x[xb];
    const float x1 = x[xb + 4096];
    const float x2 = x[xb + 8192];
    const float x3 = x[xb + 12288];
    const float a  = ((x0 * x0 + x1 * x1) + x2 * x2) + x3 * x3;

    // min over chunks, tie -> smaller chunk id (lexicographic)
    float bd = FLT_MAX;
    int   bc = 0x7fffffff;
#pragma unroll 8
    for (int i = 0; i < NC / 8; ++i) {
        const int c = sub + 8 * i;             // ascending per sub
        float d = dmn[c * NPTS + p];
        if (d < bd) { bd = d; bc = c; }        // strict <: earliest c in sub set
    }
#pragma unroll
    for (int m = 1; m <= 4; m <<= 1) {
        float d2 = __shfl_xor(bd, m);
        int   c2 = __shfl_xor(bc, m);
        if (d2 < bd || (d2 == bd && c2 < bc)) { bd = d2; bc = c2; }
    }

    // rescan chunk bc: sub handles CHUNK/8 consecutive codes
    const int kb = bc * CHUNK;
    int jloc = 1 << 30;
    for (int jj = 0; jj < CHUNK / 8; ++jj) {
        const int j = sub * (CHUNK / 8) + jj;
        float4 e = ((const float4*)E)[kb + j];
        float bn = ((e.x * e.x + e.y * e.y) + e.z * e.z) + e.w * e.w;
        float m_ = __builtin_fmaf(x3, e.w, __builtin_fmaf(x2, e.z,
                    __builtin_fmaf(x1, e.y, x0 * e.x)));
        float t_ = a + bn;
        float d_ = __builtin_fmaf(-2.0f, m_, t_);
        if (d_ == bd) jloc = min(jloc, j);     // ascending j -> first match
    }
#pragma unroll
    for (int m = 1; m <= 4; m <<= 1) jloc = min(jloc, __shfl_xor(jloc, m));
    const int bk = kb + (jloc & (CHUNK - 1));  // clamp guards OOB if mismatch

    double ls = 0.0;
    if (sub < 4) {                             // one channel per sub-lane
        const int ch  = sub;
        const int idx = xb + ch * 4096;
        float xv   = x[idx];
        float ev   = E[bk * 4 + ch];
        float diff = ev - xv;                  // fl(z_q - x)
        float sq   = diff * diff;              // fl(diff^2)
        out[idx]   = xv + diff;                // z_q_st = fl(x + fl(z_q - x))
        ls = (double)sq;
        if (ch == 0) out[32769 + p] = (float)bk;  // codes as float
    }
#pragma unroll
    for (int m = 1; m < 64; m <<= 1) ls += __shfl_xor(ls, m);
    __shared__ double sred[4];
    if ((tid & 63) == 0) sred[tid >> 6] = ls;
    __syncthreads();
    if (tid == 0) partials[blockIdx.x] = sred[0] + sred[1] + sred[2] + sred[3];
}

// ---------------- K3: finalize qloss
__global__ void k_loss(const double* __restrict__ partials,
                       float* __restrict__ out) {
#pragma clang fp contract(off)
    if (threadIdx.x == 0 && blockIdx.x == 0) {
        double sum = 0.0;
        for (int i = 0; i < 256; ++i) sum += partials[i];
        float mu = (float)(sum * (1.0 / 32768.0));   // /32768 exact
        float q  = mu + 0.1f * mu;                   // mean1 + BETA*mean2
        out[32768] = q;
    }
}

extern "C" void kernel_launch(void* const* d_in, const int* in_sizes, int n_in,
                              void* d_out, int out_size, void* d_ws, size_t ws_size,
                              hipStream_t stream) {
    const float* x = (const float*)d_in[0];   // (1,2,4,64,64)
    const float* E = (const float*)d_in[1];   // (32768,4)
    float* out = (float*)d_out;               // 40961 floats

    char* ws = (char*)d_ws;
    double* partials = (double*)ws;                    // 2 KB
    float*  dmn      = (float*)(ws + 2048);

    // dmn bytes = NC*8192*4: NC=512 -> 16 MiB (footprint proven R10/R13)
    const size_t need512 = 2048 + (size_t)512 * NPTS * 4;
    if (ws_size >= need512) {
        dim3 g(512, NPB);
        k_dist<512><<<g, TPB, 0, stream>>>(x, E, dmn);
        k_merge<512><<<NPTS / 32, 256, 0, stream>>>(x, E, dmn, out, partials);
    } else {
        dim3 g(256, NPB);
        k_dist<256><<<g, TPB, 0, stream>>>(x, E, dmn);
        k_merge<256><<<NPTS / 32, 256, 0, stream>>>(x, E, dmn, out, partials);
    }
    k_loss<<<1, 64, 0, stream>>>(partials, out);
}

// Round 15
// 51.134 us; speedup vs baseline: 4.2279x; 1.0652x over previous
//
#include <hip/hip_runtime.h>
#include <cfloat>

#define KC    32768
#define NPTS  8192
#define TPB   256
#define PPT   16
#define PTS_PER_BLK (TPB * PPT)        // 4096
#define NPB   (NPTS / PTS_PER_BLK)     // 2
#define NC    256
#define CHUNK (KC / NC)                // 128

typedef float v2f __attribute__((ext_vector_type(2)));

// Packed fp32 (IEEE per 32-bit half) — bit-identical to scalar chain (verified R1-R12)
__device__ __forceinline__ v2f pk_fma(v2f a, v2f b, v2f c) {
    v2f d; asm("v_pk_fma_f32 %0, %1, %2, %3" : "=v"(d) : "v"(a), "v"(b), "v"(c)); return d;
}
__device__ __forceinline__ v2f pk_add(v2f a, v2f b) {
    v2f d; asm("v_pk_add_f32 %0, %1, %2" : "=v"(d) : "v"(a), "v"(b)); return d;
}
// Broadcast half H of PAIR src0 to both result halves (VOP3P op_sel; verified R12)
template<int H>
__device__ __forceinline__ v2f pk_mul_s(v2f a, v2f b) {
    v2f d;
    if constexpr (H == 0)
        asm("v_pk_mul_f32 %0, %1, %2 op_sel:[0,0] op_sel_hi:[0,1]" : "=v"(d) : "v"(a), "v"(b));
    else
        asm("v_pk_mul_f32 %0, %1, %2 op_sel:[1,0] op_sel_hi:[1,1]" : "=v"(d) : "v"(a), "v"(b));
    return d;
}
template<int H>
__device__ __forceinline__ v2f pk_fma_s(v2f a, v2f b, v2f c) {
    v2f d;
    if constexpr (H == 0)
        asm("v_pk_fma_f32 %0, %1, %2, %3 op_sel:[0,0,0] op_sel_hi:[0,1,1]" : "=v"(d) : "v"(a), "v"(b), "v"(c));
    else
        asm("v_pk_fma_f32 %0, %1, %2, %3 op_sel:[1,0,0] op_sel_hi:[1,1,1]" : "=v"(d) : "v"(a), "v"(b), "v"(c));
    return d;
}
__device__ __forceinline__ float min3f(float a, float b, float c) {
    float d; asm("v_min3_f32 %0, %1, %2, %3" : "=v"(d) : "v"(a), "v"(b), "v"(c)); return d;
}

// ---------------- K1: per-chunk MIN-DISTANCE ONLY, 16 points/thread,
// software-pipelined LDS reads (prefetch q+1 while computing q).
__global__ __launch_bounds__(TPB) void k_dist(const float* __restrict__ x,
                                              const float* __restrict__ E,
                                              float* __restrict__ dmn) {
#pragma clang fp contract(off)
    __shared__ __align__(16) float lds[5 * CHUNK];
    float* exL = lds;
    float* eyL = lds + CHUNK;
    float* ezL = lds + 2 * CHUNK;
    float* ewL = lds + 3 * CHUNK;
    float* bL  = lds + 4 * CHUNK;

    const int chunk = blockIdx.x;
    const int pblk  = blockIdx.y;
    const int tid   = threadIdx.x;
    const int kbase = chunk * CHUNK;

    // Stage SoA + fused bnorm (squares individually rounded, sequential adds)
    for (int i = tid; i < CHUNK; i += TPB) {
        float4 e = ((const float4*)E)[kbase + i];
        exL[i] = e.x; eyL[i] = e.y; ezL[i] = e.z; ewL[i] = e.w;
        bL[i]  = ((e.x * e.x + e.y * e.y) + e.z * e.z) + e.w * e.w;
    }
    __syncthreads();

    // 16 points/thread: packed pairs X01={x0,x1}, X23={x2,x3}, Av={a,a}
    v2f X01[PPT], X23[PPT], Av[PPT];
#pragma unroll
    for (int i = 0; i < PPT; ++i) {
        const int p  = pblk * PTS_PER_BLK + i * TPB + tid;
        const int t  = p >> 12, s = p & 4095;
        const int xb = t * 16384 + s;
        const float x0 = x[xb];
        const float x1 = x[xb + 4096];
        const float x2 = x[xb + 8192];
        const float x3 = x[xb + 12288];
        X01[i] = v2f{x0, x1};
        X23[i] = v2f{x2, x3};
        const float a = ((x0 * x0 + x1 * x1) + x2 * x2) + x3 * x3;
        Av[i] = v2f{a, a};
    }
    const v2f M2 = {-2.0f, -2.0f};

    float bd[PPT];
#pragma unroll
    for (int i = 0; i < PPT; ++i) bd[i] = FLT_MAX;

    // software pipeline: cur regs hold iter q, prefetch q+1 before computing
    float4 cx = *(const float4*)(exL);
    float4 cy = *(const float4*)(eyL);
    float4 cz = *(const float4*)(ezL);
    float4 cw = *(const float4*)(ewL);
    float4 cb = *(const float4*)(bL);

    for (int q = 0; q < CHUNK / 4; ++q) {      // 4 codes x 16 points per iter
        const int qn = (q + 1 < CHUNK / 4) ? (q + 1) : q;
        float4 nx = *(const float4*)(exL + 4 * qn);
        float4 ny = *(const float4*)(eyL + 4 * qn);
        float4 nz = *(const float4*)(ezL + 4 * qn);
        float4 nw = *(const float4*)(ewL + 4 * qn);
        float4 nb = *(const float4*)(bL  + 4 * qn);

        const v2f ex0 = {cx.x, cx.y}, ex1 = {cx.z, cx.w};
        const v2f ey0 = {cy.x, cy.y}, ey1 = {cy.z, cy.w};
        const v2f ez0 = {cz.x, cz.y}, ez1 = {cz.z, cz.w};
        const v2f ew0 = {cw.x, cw.y}, ew1 = {cw.z, cw.w};
        const v2f b0  = {cb.x, cb.y}, b1  = {cb.z, cb.w};

#pragma unroll
        for (int i = 0; i < PPT; ++i) {
            // m = fma(x3,ew, fma(x2,ez, fma(x1,ey, x0*ex)))  (BLAS chain, R1-verified)
            v2f m0 = pk_fma_s<1>(X23[i], ew0, pk_fma_s<0>(X23[i], ez0,
                      pk_fma_s<1>(X01[i], ey0, pk_mul_s<0>(X01[i], ex0))));
            v2f m1 = pk_fma_s<1>(X23[i], ew1, pk_fma_s<0>(X23[i], ez1,
                      pk_fma_s<1>(X01[i], ey1, pk_mul_s<0>(X01[i], ex1))));
            // d = fma(-2,m,(a+b)) == (a+b) - fl(2m) bitwise
            v2f d0 = pk_fma(M2, m0, pk_add(Av[i], b0));
            v2f d1 = pk_fma(M2, m1, pk_add(Av[i], b1));
            bd[i] = min3f(min3f(bd[i], d0.x, d0.y), d1.x, d1.y);  // min only
        }
        cx = nx; cy = ny; cz = nz; cw = nw; cb = nb;
    }
#pragma unroll
    for (int i = 0; i < PPT; ++i) {
        const int p = pblk * PTS_PER_BLK + i * TPB + tid;
        dmn[chunk * NPTS + p] = bd[i];
    }
}

// ---------------- K2: merge chunk-mins, recover first-index k, gather, loss
// (verified absmax 0.0 in R12 at NC=256)
__global__ __launch_bounds__(256) void k_merge(const float* __restrict__ x,
                                               const float* __restrict__ E,
                                               const float* __restrict__ dmn,
                                               float* __restrict__ out,
                                               double* __restrict__ partials) {
#pragma clang fp contract(off)
    const int tid  = threadIdx.x;
    const int sub  = tid & 7;
    const int pidx = tid >> 3;                 // 0..31
    const int p    = blockIdx.x * 32 + pidx;   // 256 blocks x 32 points
    const int t    = p >> 12, s = p & 4095;
    const int xb   = t * 16384 + s;

    const float x0 = x[xb];
    const float x1 = x[xb + 4096];
    const float x2 = x[xb + 8192];
    const float x3 = x[xb + 12288];
    const float a  = ((x0 * x0 + x1 * x1) + x2 * x2) + x3 * x3;

    // min over chunks, tie -> smaller chunk id (lexicographic)
    float bd = FLT_MAX;
    int   bc = 0x7fffffff;
#pragma unroll 8
    for (int i = 0; i < NC / 8; ++i) {
        const int c = sub + 8 * i;             // ascending per sub
        float d = dmn[c * NPTS + p];
        if (d < bd) { bd = d; bc = c; }        // strict <: earliest c in sub set
    }
#pragma unroll
    for (int m = 1; m <= 4; m <<= 1) {
        float d2 = __shfl_xor(bd, m);
        int   c2 = __shfl_xor(bc, m);
        if (d2 < bd || (d2 == bd && c2 < bc)) { bd = d2; bc = c2; }
    }

    // rescan chunk bc: sub handles CHUNK/8 = 16 consecutive codes
    const int kb = bc * CHUNK;
    int jloc = 1 << 30;
    for (int jj = 0; jj < CHUNK / 8; ++jj) {
        const int j = sub * (CHUNK / 8) + jj;
        float4 e = ((const float4*)E)[kb + j];
        float bn = ((e.x * e.x + e.y * e.y) + e.z * e.z) + e.w * e.w;
        float m_ = __builtin_fmaf(x3, e.w, __builtin_fmaf(x2, e.z,
                    __builtin_fmaf(x1, e.y, x0 * e.x)));
        float t_ = a + bn;
        float d_ = __builtin_fmaf(-2.0f, m_, t_);
        if (d_ == bd) jloc = min(jloc, j);     // ascending j -> first match
    }
#pragma unroll
    for (int m = 1; m <= 4; m <<= 1) jloc = min(jloc, __shfl_xor(jloc, m));
    const int bk = kb + (jloc & (CHUNK - 1));  // clamp guards OOB if mismatch

    double ls = 0.0;
    if (sub < 4) {                             // one channel per sub-lane
        const int ch  = sub;
        const int idx = xb + ch * 4096;
        float xv   = x[idx];
        float ev   = E[bk * 4 + ch];
        float diff = ev - xv;                  // fl(z_q - x)
        float sq   = diff * diff;              // fl(diff^2)
        out[idx]   = xv + diff;                // z_q_st = fl(x + fl(z_q - x))
        ls = (double)sq;
        if (ch == 0) out[32769 + p] = (float)bk;  // codes as float
    }
#pragma unroll
    for (int m = 1; m < 64; m <<= 1) ls += __shfl_xor(ls, m);
    __shared__ double sred[4];
    if ((tid & 63) == 0) sred[tid >> 6] = ls;
    __syncthreads();
    if (tid == 0) partials[blockIdx.x] = sred[0] + sred[1] + sred[2] + sred[3];
}

// ---------------- K3: finalize qloss
__global__ void k_loss(const double* __restrict__ partials,
                       float* __restrict__ out) {
#pragma clang fp contract(off)
    if (threadIdx.x == 0 && blockIdx.x == 0) {
        double sum = 0.0;
        for (int i = 0; i < 256; ++i) sum += partials[i];
        float mu = (float)(sum * (1.0 / 32768.0));   // /32768 exact
        float q  = mu + 0.1f * mu;                   // mean1 + BETA*mean2
        out[32768] = q;
    }
}

extern "C" void kernel_launch(void* const* d_in, const int* in_sizes, int n_in,
                              void* d_out, int out_size, void* d_ws, size_t ws_size,
                              hipStream_t stream) {
    const float* x = (const float*)d_in[0];   // (1,2,4,64,64)
    const float* E = (const float*)d_in[1];   // (32768,4)
    float* out = (float*)d_out;               // 40961 floats

    char* ws = (char*)d_ws;
    double* partials = (double*)ws;                    // 2 KB
    float*  dmn      = (float*)(ws + 2048);            // 256*8192*4 = 8.4 MB (proven R12)

    dim3 g(NC, NPB);
    k_dist<<<g, TPB, 0, stream>>>(x, E, dmn);
    k_merge<<<NPTS / 32, 256, 0, stream>>>(x, E, dmn, out, partials);
    k_loss<<<1, 64, 0, stream>>>(partials, out);
}